// Round 13
// baseline (104.615 us; speedup 1.0000x reference)
//
#include <hip/hip_runtime.h>

#define D 128
#define TILE_N 16      // 16 nodes/block; wave w = 16 nodes x 32 cols (8 MFMAs)
#define HPITCH 132     // bf16 pitch for epilogue LDS tile
#define CAP 48         // bucket capacity per node; Poisson(12), P(deg>48) ~ 1e-14
#define SPILL_MAX 8192

typedef __attribute__((ext_vector_type(8))) short  short8;
typedef __attribute__((ext_vector_type(4))) float  f32x4;

__device__ inline unsigned short f32_to_bf16(float f) {
    unsigned int u = __float_as_uint(f);
    unsigned int r = (u + 0x7FFFu + ((u >> 16) & 1u)) >> 16;   // RNE
    return (unsigned short)r;
}
__device__ inline float bf16_to_f32(unsigned short s) {
    return __uint_as_float(((unsigned int)s) << 16);
}
__device__ inline short8 pack_bf16x8(float4 a, float4 b) {
    short8 u;
    u[0] = (short)f32_to_bf16(a.x); u[1] = (short)f32_to_bf16(a.y);
    u[2] = (short)f32_to_bf16(a.z); u[3] = (short)f32_to_bf16(a.w);
    u[4] = (short)f32_to_bf16(b.x); u[5] = (short)f32_to_bf16(b.y);
    u[6] = (short)f32_to_bf16(b.z); u[7] = (short)f32_to_bf16(b.w);
    return u;
}

// ---- prep: W->Wb, x->xb (bf16), mask->mbits (1 bit), zero cnt --------------
__global__ __launch_bounds__(256) void prep_kernel(
    const float* __restrict__ W, unsigned short* __restrict__ Wb,
    const float* __restrict__ x, unsigned short* __restrict__ xb,
    const float* __restrict__ mask_u, unsigned char* __restrict__ mbits,
    int* __restrict__ cnt, int n_nodes, int* __restrict__ spill_cnt)
{
    const int tid = blockIdx.x * 256 + threadIdx.x;
    const int nth = gridDim.x * 256;

    for (int i = tid; i < (D * D) / 8; i += nth) {
        float4 v0 = *(const float4*)&W[i * 8];
        float4 v1 = *(const float4*)&W[i * 8 + 4];
        *(short8*)&Wb[i * 8] = pack_bf16x8(v0, v1);
    }
    const int nx8 = n_nodes * (D / 8);
    for (int i = tid; i < nx8; i += nth) {
        float4 v0 = *(const float4*)&x[(size_t)i * 8];
        float4 v1 = *(const float4*)&x[(size_t)i * 8 + 4];
        *(short8*)&xb[(size_t)i * 8] = pack_bf16x8(v0, v1);
    }
    for (int i = tid; i < nx8; i += nth) {
        float4 m0 = *(const float4*)&mask_u[(size_t)i * 8];
        float4 m1 = *(const float4*)&mask_u[(size_t)i * 8 + 4];
        unsigned b = 0;
        b |= (m0.x >= 0.5f) ? 1u : 0u;   b |= (m0.y >= 0.5f) ? 2u : 0u;
        b |= (m0.z >= 0.5f) ? 4u : 0u;   b |= (m0.w >= 0.5f) ? 8u : 0u;
        b |= (m1.x >= 0.5f) ? 16u : 0u;  b |= (m1.y >= 0.5f) ? 32u : 0u;
        b |= (m1.z >= 0.5f) ? 64u : 0u;  b |= (m1.w >= 0.5f) ? 128u : 0u;
        mbits[i] = (unsigned char)b;
    }
    for (int i = tid; i < n_nodes; i += nth) cnt[i] = 0;
    if (tid == 0 && spill_cnt) *spill_cnt = 0;
}

// ---- scatter: edge -> fixed-cap bucket (ISOLATED for profiling) ------------
// Non-temporal bucket store: each random 4B write dirties a 64B line anyway;
// nt bypasses the cross-XCD L2 RFO bounce.
__global__ __launch_bounds__(256) void scatter_kernel(
    const int* __restrict__ src, const int* __restrict__ dst, int n_edges,
    int* __restrict__ cnt, int* __restrict__ bucket,
    int* __restrict__ spill_cnt, int* __restrict__ spill)
{
    const int i = blockIdx.x * 256 + threadIdx.x;
    if (i >= n_edges) return;
    const int dd = dst[i];
    const int ss = src[i];
    int pos = atomicAdd(&cnt[dd], 1);
    if (pos < CAP) {
        __builtin_nontemporal_store(ss, &bucket[dd * CAP + pos]);
    } else {
        int k = atomicAdd(spill_cnt, 1);
        if (k < SPILL_MAX) { spill[2 * k] = dd; spill[2 * k + 1] = ss; }
    }
}

// ---- GEMM (pure): h(bf16) = relu(xb @ Wb^T + b) * mbits * 2 ----------------
__global__ __launch_bounds__(256, 8) void gemm_mfma_kernel(
    const unsigned short* __restrict__ xb, const unsigned short* __restrict__ Wb,
    const float* __restrict__ bias, const unsigned char* __restrict__ mbits,
    unsigned short* __restrict__ h, int n_nodes)
{
    __shared__ unsigned short ht[TILE_N * HPITCH];   // 4224 B
    const int t    = threadIdx.x;
    const int lane = t & 63;
    const int w    = t >> 6;      // col quarter
    const int fr   = lane & 15;
    const int fg   = lane >> 4;
    const int n0 = blockIdx.x * TILE_N;

    // epilogue mask byte (thread t -> row t>>4, colgroup t&15)
    const int prow = t >> 4;
    const int pcg  = t & 15;
    const int pnode = n0 + prow;
    const bool pvalid = (pnode < n_nodes);
    unsigned mbyte = 0;
    if (pvalid) mbyte = mbits[pnode * 16 + pcg];

    // A fragments (bf16, 16B/lane x 4 ksteps)
    int arow = n0 + fr;
    if (arow >= n_nodes) arow = n_nodes - 1;
    const unsigned short* xr = xb + (size_t)arow * D;
    short8 a0 = *(const short8*)&xr[ 0 + fg * 8];
    short8 a1 = *(const short8*)&xr[32 + fg * 8];
    short8 a2 = *(const short8*)&xr[64 + fg * 8];
    short8 a3 = *(const short8*)&xr[96 + fg * 8];

    const float bs0 = bias[32 * w + fr];
    const float bs1 = bias[32 * w + 16 + fr];

    const unsigned short* wb0 = Wb + (size_t)(32 * w + fr) * D;
    const unsigned short* wb1 = Wb + (size_t)(32 * w + 16 + fr) * D;

    f32x4 acc0 = (f32x4){0.f, 0.f, 0.f, 0.f};
    f32x4 acc1 = (f32x4){0.f, 0.f, 0.f, 0.f};
    #pragma unroll
    for (int s = 0; s < 4; ++s) {
        short8 a = (s == 0) ? a0 : (s == 1) ? a1 : (s == 2) ? a2 : a3;
        short8 b0 = *(const short8*)&wb0[s * 32 + fg * 8];
        short8 b1 = *(const short8*)&wb1[s * 32 + fg * 8];
        acc0 = __builtin_amdgcn_mfma_f32_16x16x32_bf16(a, b0, acc0, 0, 0, 0);
        acc1 = __builtin_amdgcn_mfma_f32_16x16x32_bf16(a, b1, acc1, 0, 0, 0);
    }

    // phase 1: bias + relu -> LDS tile
    #pragma unroll
    for (int r = 0; r < 4; ++r) {
        const int rl = fg * 4 + r;
        float v0 = fmaxf(acc0[r] + bs0, 0.f);
        float v1 = fmaxf(acc1[r] + bs1, 0.f);
        ht[rl * HPITCH + 32 * w + fr]      = f32_to_bf16(v0);
        ht[rl * HPITCH + 32 * w + 16 + fr] = f32_to_bf16(v1);
    }
    __syncthreads();

    // phase 2: dropout via bitmask + coalesced h stores
    if (pvalid) {
        short8 hv = *(const short8*)&ht[prow * HPITCH + pcg * 8];
        short8 o;
        #pragma unroll
        for (int j = 0; j < 8; ++j) {
            float v = bf16_to_f32((unsigned short)hv[j]) * 2.f;
            o[j] = ((mbyte >> j) & 1u) ? (short)f32_to_bf16(v) : (short)0;
        }
        *(short8*)&h[(size_t)pnode * D + pcg * 8] = o;
    }
}

// ---- Gather-reduce (bf16 h): 16 lanes/node over fixed-cap buckets ----------
__global__ __launch_bounds__(256) void gather_reduce_kernel(
    const unsigned short* __restrict__ h, const int* __restrict__ cnt,
    const int* __restrict__ bucket, float* __restrict__ out, int n_nodes)
{
    const int t = threadIdx.x;
    const int node = blockIdx.x * 16 + (t >> 4);
    if (node >= n_nodes) return;
    const int cb = (t & 15) * 8;
    int deg = cnt[node];
    if (deg > CAP) deg = CAP;
    const int* b = bucket + (size_t)node * CAP;

    float acc[8];
    #pragma unroll
    for (int j = 0; j < 8; ++j) acc[j] = 0.f;

    int i = 0;
    for (; i + 3 < deg; i += 4) {
        int s0 = b[i], s1 = b[i + 1], s2 = b[i + 2], s3 = b[i + 3];
        short8 v0 = *(const short8*)&h[(size_t)s0 * D + cb];
        short8 v1 = *(const short8*)&h[(size_t)s1 * D + cb];
        short8 v2 = *(const short8*)&h[(size_t)s2 * D + cb];
        short8 v3 = *(const short8*)&h[(size_t)s3 * D + cb];
        #pragma unroll
        for (int j = 0; j < 8; ++j)
            acc[j] += (bf16_to_f32((unsigned short)v0[j]) +
                       bf16_to_f32((unsigned short)v1[j])) +
                      (bf16_to_f32((unsigned short)v2[j]) +
                       bf16_to_f32((unsigned short)v3[j]));
    }
    for (; i < deg; ++i) {
        int s0 = b[i];
        short8 v0 = *(const short8*)&h[(size_t)s0 * D + cb];
        #pragma unroll
        for (int j = 0; j < 8; ++j) acc[j] += bf16_to_f32((unsigned short)v0[j]);
    }

    f32x4 o0 = (f32x4){acc[0], acc[1], acc[2], acc[3]};
    f32x4 o1 = (f32x4){acc[4], acc[5], acc[6], acc[7]};
    __builtin_nontemporal_store(o0, (f32x4*)&out[(size_t)node * D + cb]);
    __builtin_nontemporal_store(o1, (f32x4*)&out[(size_t)node * D + cb + 4]);
}

// ---- spill fix (virtually never runs) --------------------------------------
__global__ __launch_bounds__(256) void spill_apply_kernel(
    const unsigned short* __restrict__ h, const int* __restrict__ spill_cnt,
    const int* __restrict__ spill, float* __restrict__ out)
{
    int n = *spill_cnt;
    if (n > SPILL_MAX) n = SPILL_MAX;
    for (int e = threadIdx.x; e < n; e += 256) {
        int dd = spill[2 * e], ss = spill[2 * e + 1];
        for (int j = 0; j < D; ++j)
            atomicAdd(&out[(size_t)dd * D + j],
                      bf16_to_f32(h[(size_t)ss * D + j]));
    }
}

// ---- fallback path (only if ws too small; never expected) ------------------
__global__ __launch_bounds__(256) void zero_kernel(int* __restrict__ p, int n)
{
    int i = blockIdx.x * 256 + threadIdx.x;
    if (i < n) p[i] = 0;
}

__global__ __launch_bounds__(256) void gemm_fb_kernel(
    const float* __restrict__ x, const float* __restrict__ W,
    const float* __restrict__ bias, const float* __restrict__ mask_u,
    unsigned short* __restrict__ h, int n_nodes)
{
    int tid = blockIdx.x * 256 + threadIdx.x;
    if (tid >= n_nodes * 16) return;
    int node = tid >> 4, cg = tid & 15;
    for (int c = 0; c < 8; ++c) {
        int col = cg * 8 + c;
        float s = bias[col];
        for (int k = 0; k < D; ++k)
            s += bf16_to_f32(f32_to_bf16(x[(size_t)node * D + k])) *
                 bf16_to_f32(f32_to_bf16(W[(size_t)col * D + k]));
        s = fmaxf(s, 0.f);
        float m = mask_u[(size_t)node * D + col];
        s *= (m >= 0.5f) ? 2.f : 0.f;
        h[(size_t)node * D + col] = f32_to_bf16(s);
    }
}

__global__ __launch_bounds__(256) void scatter_atomic_kernel(
    const unsigned short* __restrict__ h, const int* __restrict__ src,
    const int* __restrict__ dst, float* __restrict__ out, int n_edges)
{
    const int t = threadIdx.x;
    const int e = blockIdx.x * 16 + (t >> 4);
    if (e >= n_edges) return;
    const int cb = (t & 15) * 8;
    const int s  = src[e];
    const int dd = dst[e];
    short8 v = *(const short8*)&h[(size_t)s * D + cb];
    float* o = &out[(size_t)dd * D + cb];
    #pragma unroll
    for (int j = 0; j < 8; ++j) atomicAdd(o + j, bf16_to_f32((unsigned short)v[j]));
}

extern "C" void kernel_launch(void* const* d_in, const int* in_sizes, int n_in,
                              void* d_out, int out_size, void* d_ws, size_t ws_size,
                              hipStream_t stream) {
    const float* x      = (const float*)d_in[0];
    const float* W      = (const float*)d_in[1];
    const float* bias   = (const float*)d_in[2];
    const float* mask_u = (const float*)d_in[3];
    const int*   src    = (const int*)d_in[4];
    const int*   dst    = (const int*)d_in[5];
    float* out = (float*)d_out;

    const int n_nodes = in_sizes[0] / D;
    const int n_edges = in_sizes[4];
    const int n_tiles = (n_nodes + TILE_N - 1) / TILE_N;

    // ws: [Wb][xb][h][cnt][spill_cnt][spill][bucket][mbits]
    const size_t wb_bytes = (size_t)D * D * sizeof(unsigned short);
    const size_t xb_bytes = (size_t)n_nodes * D * sizeof(unsigned short);
    const size_t h_bytes  = (size_t)n_nodes * D * sizeof(unsigned short);
    unsigned short* Wb = (unsigned short*)d_ws;
    unsigned short* xb = (unsigned short*)((char*)d_ws + wb_bytes);
    unsigned short* h  = (unsigned short*)((char*)d_ws + wb_bytes + xb_bytes);
    int* cnt       = (int*)((char*)d_ws + wb_bytes + xb_bytes + h_bytes);
    int* spill_cnt = cnt + n_nodes;
    int* spill     = spill_cnt + 1;
    int* bucket    = spill + 2 * SPILL_MAX;
    unsigned char* mbits = (unsigned char*)(bucket + (size_t)n_nodes * CAP);
    const size_t needed = wb_bytes + xb_bytes + h_bytes +
        ((size_t)n_nodes + 1 + 2 * SPILL_MAX + (size_t)n_nodes * CAP) * sizeof(int) +
        (size_t)n_nodes * 16;

    if (ws_size >= needed) {
        prep_kernel<<<2048, 256, 0, stream>>>(
            W, Wb, x, xb, mask_u, mbits, cnt, n_nodes, spill_cnt);
        scatter_kernel<<<(n_edges + 255) / 256, 256, 0, stream>>>(
            src, dst, n_edges, cnt, bucket, spill_cnt, spill);
        gemm_mfma_kernel<<<n_tiles, 256, 0, stream>>>(
            xb, Wb, bias, mbits, h, n_nodes);
        gather_reduce_kernel<<<(n_nodes + 15) / 16, 256, 0, stream>>>(
            h, cnt, bucket, out, n_nodes);
        spill_apply_kernel<<<1, 256, 0, stream>>>(h, spill_cnt, spill, out);
    } else {
        unsigned short* hf = (unsigned short*)d_ws;   // only h fits
        gemm_fb_kernel<<<(n_nodes * 16 + 255) / 256, 256, 0, stream>>>(
            x, W, bias, mask_u, hf, n_nodes);
        zero_kernel<<<(out_size + 255) / 256, 256, 0, stream>>>((int*)d_out, out_size);
        scatter_atomic_kernel<<<(n_edges + 15) / 16, 256, 0, stream>>>(
            hf, src, dst, out, n_edges);
    }
}

// Round 14
// 78.941 us; speedup vs baseline: 1.3252x; 1.3252x over previous
//
#include <hip/hip_runtime.h>

#define D 128
#define TILE_N 16      // 16 nodes/block; wave w = 16 nodes x 32 cols (8 MFMAs)
#define HPITCH 132     // bf16 pitch for epilogue LDS tile
#define CAP 32         // ushort bucket; Poisson(12): P(deg>32)~4e-6 -> spill path
#define SPILL_MAX 8192

typedef __attribute__((ext_vector_type(8))) short  short8;
typedef __attribute__((ext_vector_type(4))) float  f32x4;

__device__ inline unsigned short f32_to_bf16(float f) {
    unsigned int u = __float_as_uint(f);
    unsigned int r = (u + 0x7FFFu + ((u >> 16) & 1u)) >> 16;   // RNE
    return (unsigned short)r;
}
__device__ inline float bf16_to_f32(unsigned short s) {
    return __uint_as_float(((unsigned int)s) << 16);
}
__device__ inline short8 pack_bf16x8(float4 a, float4 b) {
    short8 u;
    u[0] = (short)f32_to_bf16(a.x); u[1] = (short)f32_to_bf16(a.y);
    u[2] = (short)f32_to_bf16(a.z); u[3] = (short)f32_to_bf16(a.w);
    u[4] = (short)f32_to_bf16(b.x); u[5] = (short)f32_to_bf16(b.y);
    u[6] = (short)f32_to_bf16(b.z); u[7] = (short)f32_to_bf16(b.w);
    return u;
}

// ---- prep: W->Wb, x->xb (bf16), mask->mbits (1 bit), zero cnt --------------
__global__ __launch_bounds__(256) void prep_kernel(
    const float* __restrict__ W, unsigned short* __restrict__ Wb,
    const float* __restrict__ x, unsigned short* __restrict__ xb,
    const float* __restrict__ mask_u, unsigned char* __restrict__ mbits,
    int* __restrict__ cnt, int n_nodes, int* __restrict__ spill_cnt)
{
    const int tid = blockIdx.x * 256 + threadIdx.x;
    const int nth = gridDim.x * 256;

    for (int i = tid; i < (D * D) / 8; i += nth) {
        float4 v0 = *(const float4*)&W[i * 8];
        float4 v1 = *(const float4*)&W[i * 8 + 4];
        *(short8*)&Wb[i * 8] = pack_bf16x8(v0, v1);
    }
    const int nx8 = n_nodes * (D / 8);
    for (int i = tid; i < nx8; i += nth) {
        float4 v0 = *(const float4*)&x[(size_t)i * 8];
        float4 v1 = *(const float4*)&x[(size_t)i * 8 + 4];
        *(short8*)&xb[(size_t)i * 8] = pack_bf16x8(v0, v1);
    }
    for (int i = tid; i < nx8; i += nth) {
        float4 m0 = *(const float4*)&mask_u[(size_t)i * 8];
        float4 m1 = *(const float4*)&mask_u[(size_t)i * 8 + 4];
        unsigned b = 0;
        b |= (m0.x >= 0.5f) ? 1u : 0u;   b |= (m0.y >= 0.5f) ? 2u : 0u;
        b |= (m0.z >= 0.5f) ? 4u : 0u;   b |= (m0.w >= 0.5f) ? 8u : 0u;
        b |= (m1.x >= 0.5f) ? 16u : 0u;  b |= (m1.y >= 0.5f) ? 32u : 0u;
        b |= (m1.z >= 0.5f) ? 64u : 0u;  b |= (m1.w >= 0.5f) ? 128u : 0u;
        mbits[i] = (unsigned char)b;
    }
    for (int i = tid; i < n_nodes; i += nth) cnt[i] = 0;
    if (tid == 0 && spill_cnt) *spill_cnt = 0;
}

// ---- GEMM + fused edge bucket-scatter (ushort bucket, L2-resident) ---------
__global__ __launch_bounds__(256, 8) void gemm_mfma_kernel(
    const unsigned short* __restrict__ xb, const unsigned short* __restrict__ Wb,
    const float* __restrict__ bias, const unsigned char* __restrict__ mbits,
    unsigned short* __restrict__ h, int n_nodes,
    const int* __restrict__ src, const int* __restrict__ dst, int n_edges,
    int* __restrict__ cnt, unsigned short* __restrict__ bucket,
    int* __restrict__ spill_cnt, int* __restrict__ spill)
{
    __shared__ unsigned short ht[TILE_N * HPITCH];   // 4224 B
    const int t    = threadIdx.x;
    const int lane = t & 63;
    const int w    = t >> 6;      // col quarter
    const int fr   = lane & 15;
    const int fg   = lane >> 4;
    const int n0 = blockIdx.x * TILE_N;

    // issue-early: edge pair
    const int e0 = blockIdx.x * 256 + t;
    int e_dst = 0, e_src = 0;
    const bool has_e0 = (e0 < n_edges);
    if (has_e0) { e_dst = dst[e0]; e_src = src[e0]; }

    // issue-early: epilogue mask byte
    const int prow = t >> 4;
    const int pcg  = t & 15;
    const int pnode = n0 + prow;
    const bool pvalid = (pnode < n_nodes);
    unsigned mbyte = 0;
    if (pvalid) mbyte = mbits[pnode * 16 + pcg];

    // issue-early: A fragments (bf16, 16B/lane x 4 ksteps)
    int arow = n0 + fr;
    if (arow >= n_nodes) arow = n_nodes - 1;
    const unsigned short* xr = xb + (size_t)arow * D;
    short8 a0 = *(const short8*)&xr[ 0 + fg * 8];
    short8 a1 = *(const short8*)&xr[32 + fg * 8];
    short8 a2 = *(const short8*)&xr[64 + fg * 8];
    short8 a3 = *(const short8*)&xr[96 + fg * 8];

    const float bs0 = bias[32 * w + fr];
    const float bs1 = bias[32 * w + 16 + fr];

    const unsigned short* wb0 = Wb + (size_t)(32 * w + fr) * D;
    const unsigned short* wb1 = Wb + (size_t)(32 * w + 16 + fr) * D;

    f32x4 acc0 = (f32x4){0.f, 0.f, 0.f, 0.f};
    f32x4 acc1 = (f32x4){0.f, 0.f, 0.f, 0.f};
    #pragma unroll
    for (int s = 0; s < 4; ++s) {
        short8 a = (s == 0) ? a0 : (s == 1) ? a1 : (s == 2) ? a2 : a3;
        short8 b0 = *(const short8*)&wb0[s * 32 + fg * 8];
        short8 b1 = *(const short8*)&wb1[s * 32 + fg * 8];
        acc0 = __builtin_amdgcn_mfma_f32_16x16x32_bf16(a, b0, acc0, 0, 0, 0);
        acc1 = __builtin_amdgcn_mfma_f32_16x16x32_bf16(a, b1, acc1, 0, 0, 0);
    }

    // phase 1: bias + relu -> LDS tile
    #pragma unroll
    for (int r = 0; r < 4; ++r) {
        const int rl = fg * 4 + r;
        float v0 = fmaxf(acc0[r] + bs0, 0.f);
        float v1 = fmaxf(acc1[r] + bs1, 0.f);
        ht[rl * HPITCH + 32 * w + fr]      = f32_to_bf16(v0);
        ht[rl * HPITCH + 32 * w + 16 + fr] = f32_to_bf16(v1);
    }
    __syncthreads();

    // fused bucket-scatter (temporal ushort store -> stays L2-resident)
    if (has_e0) {
        int pos = atomicAdd(&cnt[e_dst], 1);
        if (pos < CAP) {
            bucket[(size_t)e_dst * CAP + pos] = (unsigned short)e_src;
        } else {
            int k = atomicAdd(spill_cnt, 1);
            if (k < SPILL_MAX) { spill[2 * k] = e_dst; spill[2 * k + 1] = e_src; }
        }
    }
    const int stride = gridDim.x * 256;
    for (int i = e0 + stride; i < n_edges; i += stride) {
        int dd  = dst[i];
        int ss  = src[i];
        int pos = atomicAdd(&cnt[dd], 1);
        if (pos < CAP) {
            bucket[(size_t)dd * CAP + pos] = (unsigned short)ss;
        } else {
            int k = atomicAdd(spill_cnt, 1);
            if (k < SPILL_MAX) { spill[2 * k] = dd; spill[2 * k + 1] = ss; }
        }
    }

    // phase 2: dropout via bitmask + coalesced h stores
    if (pvalid) {
        short8 hv = *(const short8*)&ht[prow * HPITCH + pcg * 8];
        short8 o;
        #pragma unroll
        for (int j = 0; j < 8; ++j) {
            float v = bf16_to_f32((unsigned short)hv[j]) * 2.f;
            o[j] = ((mbyte >> j) & 1u) ? (short)f32_to_bf16(v) : (short)0;
        }
        *(short8*)&h[(size_t)pnode * D + pcg * 8] = o;
    }
}

// ---- Gather-reduce (bf16 h, ushort buckets) --------------------------------
__global__ __launch_bounds__(256) void gather_reduce_kernel(
    const unsigned short* __restrict__ h, const int* __restrict__ cnt,
    const unsigned short* __restrict__ bucket, float* __restrict__ out,
    int n_nodes)
{
    const int t = threadIdx.x;
    const int node = blockIdx.x * 16 + (t >> 4);
    if (node >= n_nodes) return;
    const int cb = (t & 15) * 8;
    int deg = cnt[node];
    if (deg > CAP) deg = CAP;
    const unsigned short* b = bucket + (size_t)node * CAP;

    float acc[8];
    #pragma unroll
    for (int j = 0; j < 8; ++j) acc[j] = 0.f;

    int i = 0;
    for (; i + 3 < deg; i += 4) {
        int s0 = b[i], s1 = b[i + 1], s2 = b[i + 2], s3 = b[i + 3];
        short8 v0 = *(const short8*)&h[(size_t)s0 * D + cb];
        short8 v1 = *(const short8*)&h[(size_t)s1 * D + cb];
        short8 v2 = *(const short8*)&h[(size_t)s2 * D + cb];
        short8 v3 = *(const short8*)&h[(size_t)s3 * D + cb];
        #pragma unroll
        for (int j = 0; j < 8; ++j)
            acc[j] += (bf16_to_f32((unsigned short)v0[j]) +
                       bf16_to_f32((unsigned short)v1[j])) +
                      (bf16_to_f32((unsigned short)v2[j]) +
                       bf16_to_f32((unsigned short)v3[j]));
    }
    for (; i < deg; ++i) {
        int s0 = b[i];
        short8 v0 = *(const short8*)&h[(size_t)s0 * D + cb];
        #pragma unroll
        for (int j = 0; j < 8; ++j) acc[j] += bf16_to_f32((unsigned short)v0[j]);
    }

    f32x4 o0 = (f32x4){acc[0], acc[1], acc[2], acc[3]};
    f32x4 o1 = (f32x4){acc[4], acc[5], acc[6], acc[7]};
    __builtin_nontemporal_store(o0, (f32x4*)&out[(size_t)node * D + cb]);
    __builtin_nontemporal_store(o1, (f32x4*)&out[(size_t)node * D + cb + 4]);
}

// ---- spill fix (rare: ~0.2 nodes exceed CAP=32) ----------------------------
__global__ __launch_bounds__(256) void spill_apply_kernel(
    const unsigned short* __restrict__ h, const int* __restrict__ spill_cnt,
    const int* __restrict__ spill, float* __restrict__ out)
{
    int n = *spill_cnt;
    if (n > SPILL_MAX) n = SPILL_MAX;
    for (int e = threadIdx.x / 16; e < n; e += 16) {
        int dd = spill[2 * e], ss = spill[2 * e + 1];
        int cb = (threadIdx.x & 15) * 8;
        short8 v = *(const short8*)&h[(size_t)ss * D + cb];
        float* o = &out[(size_t)dd * D + cb];
        #pragma unroll
        for (int j = 0; j < 8; ++j)
            atomicAdd(o + j, bf16_to_f32((unsigned short)v[j]));
    }
}

// ---- fallback path (ws too small or n_nodes > 65535) -----------------------
__global__ __launch_bounds__(256) void zero_kernel(int* __restrict__ p, int n)
{
    int i = blockIdx.x * 256 + threadIdx.x;
    if (i < n) p[i] = 0;
}

__global__ __launch_bounds__(256) void gemm_fb_kernel(
    const float* __restrict__ x, const float* __restrict__ W,
    const float* __restrict__ bias, const float* __restrict__ mask_u,
    unsigned short* __restrict__ h, int n_nodes)
{
    int tid = blockIdx.x * 256 + threadIdx.x;
    if (tid >= n_nodes * 16) return;
    int node = tid >> 4, cg = tid & 15;
    for (int c = 0; c < 8; ++c) {
        int col = cg * 8 + c;
        float s = bias[col];
        for (int k = 0; k < D; ++k)
            s += bf16_to_f32(f32_to_bf16(x[(size_t)node * D + k])) *
                 bf16_to_f32(f32_to_bf16(W[(size_t)col * D + k]));
        s = fmaxf(s, 0.f);
        float m = mask_u[(size_t)node * D + col];
        s *= (m >= 0.5f) ? 2.f : 0.f;
        h[(size_t)node * D + col] = f32_to_bf16(s);
    }
}

__global__ __launch_bounds__(256) void scatter_atomic_kernel(
    const unsigned short* __restrict__ h, const int* __restrict__ src,
    const int* __restrict__ dst, float* __restrict__ out, int n_edges)
{
    const int t = threadIdx.x;
    const int e = blockIdx.x * 16 + (t >> 4);
    if (e >= n_edges) return;
    const int cb = (t & 15) * 8;
    const int s  = src[e];
    const int dd = dst[e];
    short8 v = *(const short8*)&h[(size_t)s * D + cb];
    float* o = &out[(size_t)dd * D + cb];
    #pragma unroll
    for (int j = 0; j < 8; ++j) atomicAdd(o + j, bf16_to_f32((unsigned short)v[j]));
}

extern "C" void kernel_launch(void* const* d_in, const int* in_sizes, int n_in,
                              void* d_out, int out_size, void* d_ws, size_t ws_size,
                              hipStream_t stream) {
    const float* x      = (const float*)d_in[0];
    const float* W      = (const float*)d_in[1];
    const float* bias   = (const float*)d_in[2];
    const float* mask_u = (const float*)d_in[3];
    const int*   src    = (const int*)d_in[4];
    const int*   dst    = (const int*)d_in[5];
    float* out = (float*)d_out;

    const int n_nodes = in_sizes[0] / D;
    const int n_edges = in_sizes[4];
    const int n_tiles = (n_nodes + TILE_N - 1) / TILE_N;

    // ws: [Wb][xb][h][cnt][spill_cnt][spill][bucket ushort][mbits]
    const size_t wb_bytes = (size_t)D * D * sizeof(unsigned short);
    const size_t xb_bytes = (size_t)n_nodes * D * sizeof(unsigned short);
    const size_t h_bytes  = (size_t)n_nodes * D * sizeof(unsigned short);
    unsigned short* Wb = (unsigned short*)d_ws;
    unsigned short* xb = (unsigned short*)((char*)d_ws + wb_bytes);
    unsigned short* h  = (unsigned short*)((char*)d_ws + wb_bytes + xb_bytes);
    int* cnt       = (int*)((char*)d_ws + wb_bytes + xb_bytes + h_bytes);
    int* spill_cnt = cnt + n_nodes;
    int* spill     = spill_cnt + 1;
    unsigned short* bucket = (unsigned short*)(spill + 2 * SPILL_MAX);
    unsigned char*  mbits  = (unsigned char*)(bucket + (size_t)n_nodes * CAP);
    const size_t needed = wb_bytes + xb_bytes + h_bytes +
        ((size_t)n_nodes + 1 + 2 * SPILL_MAX) * sizeof(int) +
        (size_t)n_nodes * CAP * sizeof(unsigned short) +
        (size_t)n_nodes * 16;

    if (ws_size >= needed && n_nodes <= 65535) {
        prep_kernel<<<2048, 256, 0, stream>>>(
            W, Wb, x, xb, mask_u, mbits, cnt, n_nodes, spill_cnt);
        gemm_mfma_kernel<<<n_tiles, 256, 0, stream>>>(
            xb, Wb, bias, mbits, h, n_nodes,
            src, dst, n_edges, cnt, bucket, spill_cnt, spill);
        gather_reduce_kernel<<<(n_nodes + 15) / 16, 256, 0, stream>>>(
            h, cnt, bucket, out, n_nodes);
        spill_apply_kernel<<<1, 256, 0, stream>>>(h, spill_cnt, spill, out);
    } else {
        unsigned short* hf = (unsigned short*)d_ws;   // only h fits
        gemm_fb_kernel<<<(n_nodes * 16 + 255) / 256, 256, 0, stream>>>(
            x, W, bias, mask_u, hf, n_nodes);
        zero_kernel<<<(out_size + 255) / 256, 256, 0, stream>>>((int*)d_out, out_size);
        scatter_atomic_kernel<<<(n_edges + 15) / 16, 256, 0, stream>>>(
            hf, src, dst, out, n_edges);
    }
}